// Round 16
// baseline (134313.000 us; speedup 1.0000x reference)
//
#include <hip/hip_runtime.h>

// Problem constants
#define Bc   64
#define Tc   512
#define NINc 256
#define Hc   512
#define NOUTc 256
#define NBLK 256
#define NTHR 1024
#define NWAVE 16
#define GSZ  32      // blocks per barrier group
#define NGRP 8       // groups

__device__ __forceinline__ float fsig(float x) { return 1.f / (1.f + expf(-x)); }

// ---- sc1 data plane: relaxed agent atomics bypass L1/L2, meet at MALL ----
__device__ __forceinline__ float ldg1(const float* p) {
  return __hip_atomic_load(p, __ATOMIC_RELAXED, __HIP_MEMORY_SCOPE_AGENT);
}
__device__ __forceinline__ void stg1(float* p, float v) {
  __hip_atomic_store(p, v, __ATOMIC_RELAXED, __HIP_MEMORY_SCOPE_AGENT);
}

// ---- flat fence-free grid barrier (unchanged from R11/R15) ----
__device__ __forceinline__ void bar_arrive(unsigned* __restrict__ grp, int blk, unsigned ep) {
  asm volatile("s_waitcnt vmcnt(0)" ::: "memory");
  __syncthreads();
  if (threadIdx.x == 0)
    __hip_atomic_fetch_add(&grp[(blk >> 5) * 32], 1u,
                           __ATOMIC_RELAXED, __HIP_MEMORY_SCOPE_AGENT);
}
__device__ __forceinline__ void bar_wait(unsigned* __restrict__ grp, unsigned ep) {
  if (threadIdx.x < 64) {
    const unsigned tgt = ep * GSZ;
    for (;;) {
      bool ok = true;
      if (threadIdx.x < NGRP)
        ok = (__hip_atomic_load(&grp[threadIdx.x * 32], __ATOMIC_RELAXED,
                                __HIP_MEMORY_SCOPE_AGENT) >= tgt);
      if (__all(ok)) break;
      __builtin_amdgcn_s_sleep(1);
    }
  }
  __syncthreads();
  asm volatile("" ::: "memory");
}

// 8-term f32 fma group from a chunk-local av[8] -> f32 accumulate
#define GRP8V(W, woff, av, acc)                                  \
  {                                                              \
    float4 wa = *(const float4*)((W) + (woff));                  \
    float4 wb = *(const float4*)((W) + (woff) + 4);              \
    float p =  (av)[0] * wa.x;                                   \
    p = fmaf((av)[1], wa.y, p);                                  \
    p = fmaf((av)[2], wa.z, p);                                  \
    p = fmaf((av)[3], wa.w, p);                                  \
    p = fmaf((av)[4], wb.x, p);                                  \
    p = fmaf((av)[5], wb.y, p);                                  \
    p = fmaf((av)[6], wb.z, p);                                  \
    p = fmaf((av)[7], wb.w, p);                                  \
    (acc) += p;                                                  \
  }

#define LOAD8(av, A, base)                                       \
  _Pragma("unroll")                                              \
  for (int k = 0; k < 8; ++k) (av)[k] = ldg1((A) + ((base) + k) * Bc);

// ---- fused CD, software-pipelined 8-deep double buffer ----
// one sc1 h0 stream -> W_ih1:acc1 + W_hh0:acc0 (summation order == R15)
__device__ __forceinline__ void dot_cd32(const float* __restrict__ A,
                                         const float* __restrict__ W1, const int ws1,
                                         float* __restrict__ acc1,
                                         const float* __restrict__ W0, const int ws0,
                                         float* __restrict__ acc0) {
  float a0[8], a1[8];
#define CD_CHUNK(av, base)                                              \
  _Pragma("unroll")                                                     \
  for (int r = 0; r < 8; ++r) GRP8V(W1, r * ws1 + (base), av, acc1[r]); \
  _Pragma("unroll")                                                     \
  for (int r = 0; r < 8; ++r) GRP8V(W0, r * ws0 + (base), av, acc0[r]);
  LOAD8(a0, A, 0);
  LOAD8(a1, A, 8);
  CD_CHUNK(a0, 0);
  LOAD8(a0, A, 16);
  CD_CHUNK(a1, 8);
  LOAD8(a1, A, 24);
  CD_CHUNK(a0, 16);
  CD_CHUNK(a1, 24);
#undef CD_CHUNK
}

// ---- fused EB, pipelined: h1 stream -> W_hh1:acc1 + head row:hs ----
__device__ __forceinline__ void dot_eb32(const float* __restrict__ A,
                                         const float* __restrict__ W1, const int ws1,
                                         float* __restrict__ acc1,
                                         const float* __restrict__ Wh,
                                         float* __restrict__ hs) {
  float a0[8], a1[8];
#define EB_CHUNK(av, base)                                              \
  _Pragma("unroll")                                                     \
  for (int r = 0; r < 8; ++r) GRP8V(W1, r * ws1 + (base), av, acc1[r]); \
  GRP8V(Wh, (base), av, *hs);
  LOAD8(a0, A, 0);
  LOAD8(a1, A, 8);
  EB_CHUNK(a0, 0);
  LOAD8(a0, A, 16);
  EB_CHUNK(a1, 8);
  LOAD8(a1, A, 24);
  EB_CHUNK(a0, 16);
  EB_CHUNK(a1, 24);
#undef EB_CHUNK
}

// ---- single-acc sc1 dots, pipelined ----
__device__ __forceinline__ void dot8_a32(const float* __restrict__ A,
                                         const float* __restrict__ W,
                                         const int wstride,
                                         float* __restrict__ acc) {
  float a0[8], a1[8];
#define A_CHUNK(av, base)                                               \
  _Pragma("unroll")                                                     \
  for (int r = 0; r < 8; ++r) GRP8V(W, r * wstride + (base), av, acc[r]);
  LOAD8(a0, A, 0);
  LOAD8(a1, A, 8);
  A_CHUNK(a0, 0);
  LOAD8(a0, A, 16);
  A_CHUNK(a1, 8);
  LOAD8(a1, A, 24);
  A_CHUNK(a0, 16);
  A_CHUNK(a1, 24);
}
__device__ __forceinline__ void dot8_a16(const float* __restrict__ A,
                                         const float* __restrict__ W,
                                         const int wstride,
                                         float* __restrict__ acc) {
  float a0[8], a1[8];
  LOAD8(a0, A, 0);
  LOAD8(a1, A, 8);
  A_CHUNK(a0, 0);
  A_CHUNK(a1, 8);
}
#undef A_CHUNK

// A contiguous (raw x row, normal cached; read-only, never invalidated)
__device__ __forceinline__ void dot8_x16(const float* __restrict__ A,
                                         const float* __restrict__ W,
                                         const int wstride,
                                         float* __restrict__ acc) {
  float av[16];
#pragma unroll
  for (int kk = 0; kk < 16; kk += 4) {
    float4 v = *(const float4*)(A + kk);
    av[kk] = v.x; av[kk + 1] = v.y; av[kk + 2] = v.z; av[kk + 3] = v.w;
  }
#pragma unroll
  for (int r = 0; r < 8; ++r) GRP8V(W, r * wstride, av, acc[r]);
#pragma unroll
  for (int r = 0; r < 8; ++r) GRP8V(W, r * wstride + 8, av + 8, acc[r]);
}

__device__ __forceinline__ void write_plane(float* __restrict__ pb,
                                            const float* __restrict__ acc,
                                            int kg, int b) {
#pragma unroll
  for (int r = 0; r < 8; ++r) pb[(kg * 8 + r) * 64 + b] = acc[r];
}

__device__ __forceinline__ float sum_planes_f(const float* __restrict__ pb,
                                              int r, int b) {
  float s = 0.f;
#pragma unroll
  for (int p = 0; p < NWAVE; ++p) s += pb[(p * 8 + r) * 64 + b];
  return s;
}

extern "C" __global__ __launch_bounds__(NTHR, 4)
void lstm_seq_kernel(const float* __restrict__ x,      // [B,T,NIN]
                     const float* __restrict__ h0in,   // [L,B,H]
                     const float* __restrict__ c0in,   // [L,B,H]
                     const float* __restrict__ Wih0,   // [4H,NIN]
                     const float* __restrict__ Wih1,   // [4H,H]
                     const float* __restrict__ Whh,    // [L,4H,H]
                     const float* __restrict__ bih,    // [L,4H]
                     const float* __restrict__ bhh,    // [L,4H]
                     const float* __restrict__ Wemb,   // [NOUT,H]
                     const float* __restrict__ bemb,   // [NOUT]
                     const unsigned char* __restrict__ uprev, // [T] bool (or int32)
                     float* __restrict__ out,          // [B,T,NOUT]
                     float* __restrict__ ws) {
  __shared__ __align__(16) float wl0[8 * 768];    // [r][ W_ih0(256) | W_hh0(512) ]
  __shared__ __align__(16) float wl1[8 * 1024];   // [r][ W_ih1(512) | W_hh1(512) ]
  __shared__ __align__(16) float whd[512];        // W_emb row `blk`
  __shared__ __align__(16) float pbuf[NWAVE * 8 * 64];
  __shared__ __align__(16) float gbuf[8 * 64];    // nonlinearized gates
  __shared__ float biasesF[2][8];
  __shared__ float bembs;
  __shared__ int up_mode;

  const int tid = threadIdx.x;
  const int blk = blockIdx.x;
  const int b   = tid & 63;
  const int kg  = tid >> 6;   // wave index = K-group (0..15)
  const int j0  = blk * 2;

  // ---- workspace map (first 4 KiB control, zeroed by host memset) ----
  unsigned* grp = (unsigned*)ws;               // 8 counters, 128B apart
  float* h0p  = ws + 1024;                     // [H][B]  layer-0 h plane
  float* h1p  = h0p + Hc * Bc;                 // [H][B]  layer-1 h plane
  float* outT = h1p + Hc * Bc;                 // [NOUT][B]

  // ---- detect use_prev dtype ----
  if (tid == 0) up_mode = 1;
  __syncthreads();
  {
    int bad = 0;
    for (int idx = tid; idx < Tc; idx += NTHR)
      if ((idx & 3) && uprev[idx]) bad = 1;
    if (bad) up_mode = 0;
  }

  // ---- load weights into LDS (cached reads; never invalidated) ----
  for (int r = 0; r < 8; ++r) {
    const int u = r >> 2, g = r & 3;
    const int row = g * Hc + (j0 + u);
    const float* sA = Wih0 + (size_t)row * NINc;
    const float* sB = Whh  + (size_t)row * Hc;
    const float* sC = Wih1 + (size_t)row * Hc;
    const float* sD = Whh  + (size_t)(4 * Hc) * Hc + (size_t)row * Hc;
    for (int i = tid; i < NINc; i += NTHR) wl0[r * 768 + i] = sA[i];
    for (int i = tid; i < Hc;   i += NTHR) wl0[r * 768 + NINc + i] = sB[i];
    for (int i = tid; i < Hc;   i += NTHR) wl1[r * 1024 + i] = sC[i];
    for (int i = tid; i < Hc;   i += NTHR) wl1[r * 1024 + Hc + i] = sD[i];
    if (tid == 0)
      biasesF[0][r] = (float)((double)bih[row] + (double)bhh[row]),
      biasesF[1][r] = (float)((double)bih[4 * Hc + row] + (double)bhh[4 * Hc + row]);
  }
  for (int i = tid; i < Hc; i += NTHR) whd[i] = Wemb[(size_t)blk * Hc + i];
  if (tid == 0) bembs = bemb[blk];

  // ---- init h planes transposed to [H][B]; sc1 stores ----
  for (int idx = blk * NTHR + tid; idx < 2 * Hc * Bc; idx += NBLK * NTHR) {
    const int l   = idx / (Hc * Bc);
    const int rem = idx - l * (Hc * Bc);
    const int j   = rem >> 6;
    const int bb  = rem & 63;
    stg1((l ? h1p : h0p) + rem, h0in[((size_t)l * Bc + bb) * Hc + j]);
  }

  // ---- cell state (f64) in registers of threads 0..127 ----
  double c0r = 0.0, c1r = 0.0;
  const int cu = tid >> 6;
  if (tid < 128) {
    const int j = j0 + cu;
    c0r = (double)c0in[((size_t)0 * Bc + b) * Hc + j];
    c1r = (double)c0in[((size_t)1 * Bc + b) * Hc + j];
  }
  __syncthreads();
  const int upm = up_mode;
  const int* uprev32 = (const int*)uprev;
#define UPAT(tt) (upm ? (uprev32[tt] != 0) : (uprev[tt] != 0))

  unsigned ep = 0;
  bar_arrive(grp, blk, ++ep);   // publish h-plane init
  bar_wait(grp, ep);

  // ---- pre-loop: accL0 = W_ih0@x[0] + W_hh0@h0init; accL1 = W_hh1@h1init ----
  float accL0[8], accL1[8];
#pragma unroll
  for (int r = 0; r < 8; ++r) { accL0[r] = 0.f; accL1[r] = 0.f; }
  dot8_x16(x + ((size_t)b * Tc + 0) * NINc + kg * 16, &wl0[kg * 16], 768, accL0);
  dot8_a32(h0p + (kg * 32) * Bc + b, &wl0[NINc + kg * 32], 768, accL0);
  dot8_a32(h1p + (kg * 32) * Bc + b, &wl1[Hc + kg * 32], 1024, accL1);

  for (int t = 0; t < Tc; ++t) {
    const bool upn = (t + 1 < Tc) && UPAT(t + 1);

    // ---- 1. feedback part of L0[t] (only when scheduled sampling) ----
    if (t > 0 && UPAT(t))
      dot8_a16(outT + (kg * 16) * Bc + b, &wl0[kg * 16], 768, accL0);

    // ---- 2. L0 cell: distributed gates (512 thr), finish (128 thr), publish ----
    write_plane(pbuf, accL0, kg, b);
    __syncthreads();
    if (tid < 512) {
      const int r = kg & 7;   // kg<8 for tid<512
      float s = sum_planes_f(pbuf, r, b) + biasesF[0][r];
      gbuf[r * 64 + b] = ((r & 3) == 2) ? tanhf(s) : fsig(s);
    }
    __syncthreads();
    if (tid < 128) {
      float si = gbuf[(cu * 4 + 0) * 64 + b];
      float sf = gbuf[(cu * 4 + 1) * 64 + b];
      float sg = gbuf[(cu * 4 + 2) * 64 + b];
      float so = gbuf[(cu * 4 + 3) * 64 + b];
      double cn = (double)sf * c0r + (double)(si * sg);
      c0r = cn;
      stg1(&h0p[(j0 + cu) * Bc + b], so * tanhf((float)cn));
    }
#pragma unroll
    for (int r = 0; r < 8; ++r) accL0[r] = 0.f;
    bar_arrive(grp, blk, ++ep);

    // ---- 3. hidden behind bar1: x[t+1] part of L0[t+1] (cached) ----
    if (t + 1 < Tc && !upn)
      dot8_x16(x + ((size_t)b * Tc + (t + 1)) * NINc + kg * 16, &wl0[kg * 16], 768, accL0);

    bar_wait(grp, ep);   // h0[t] visible

    // ---- 5. fused CD: one h0[t] stream -> accL1 (W_ih1) + accL0 (W_hh0, t+1) ----
    dot_cd32(h0p + (kg * 32) * Bc + b,
             &wl1[kg * 32], 1024, accL1,
             &wl0[NINc + kg * 32], 768, accL0);

    // ---- 6. L1 cell: distributed gates, finish, publish h1[t] ----
    write_plane(pbuf, accL1, kg, b);
    __syncthreads();
    if (tid < 512) {
      const int r = kg & 7;
      float s = sum_planes_f(pbuf, r, b) + biasesF[1][r];
      gbuf[r * 64 + b] = ((r & 3) == 2) ? tanhf(s) : fsig(s);
    }
    __syncthreads();
    if (tid < 128) {
      float si = gbuf[(cu * 4 + 0) * 64 + b];
      float sf = gbuf[(cu * 4 + 1) * 64 + b];
      float sg = gbuf[(cu * 4 + 2) * 64 + b];
      float so = gbuf[(cu * 4 + 3) * 64 + b];
      double cn = (double)sf * c1r + (double)(si * sg);
      c1r = cn;
      stg1(&h1p[(j0 + cu) * Bc + b], so * tanhf((float)cn));
    }
#pragma unroll
    for (int r = 0; r < 8; ++r) accL1[r] = 0.f;
    bar_arrive(grp, blk, ++ep);
    bar_wait(grp, ep);   // h1[t] visible

    // ---- 8. fused EB: one h1[t] stream -> head partial + accL1 (W_hh1, t+1) ----
    {
      float hs = 0.f;
      dot_eb32(h1p + (kg * 32) * Bc + b,
               &wl1[Hc + kg * 32], 1024, accL1,
               &whd[kg * 32], &hs);
      pbuf[kg * 64 + b] = hs;
    }
    __syncthreads();

    // ---- 9. head finish; out + feedback publish ----
    if (tid < 64) {
      float s = bembs;
#pragma unroll
      for (int pl = 0; pl < NWAVE; ++pl) s += pbuf[pl * 64 + b];
      float o = tanhf(s);
      stg1(&outT[blk * Bc + b], o);                    // feedback buffer [NOUT][B]
      out[((size_t)b * Tc + t) * NOUTc + blk] = o;     // final output [B,T,NOUT]
    }
    if (upn) {
      bar_arrive(grp, blk, ++ep);                      // publish out[t]
      bar_wait(grp, ep);
    } else if (t + 1 < Tc) {
      __syncthreads();                                 // pbuf reuse guard
    }
  }
}

extern "C" void kernel_launch(void* const* d_in, const int* in_sizes, int n_in,
                              void* d_out, int out_size, void* d_ws, size_t ws_size,
                              hipStream_t stream) {
  const float* x    = (const float*)d_in[0];
  const float* h0   = (const float*)d_in[1];
  const float* c0   = (const float*)d_in[2];
  const float* Wih0 = (const float*)d_in[3];
  const float* Wih1 = (const float*)d_in[4];
  const float* Whh  = (const float*)d_in[5];
  const float* bih  = (const float*)d_in[6];
  const float* bhh  = (const float*)d_in[7];
  const float* Wemb = (const float*)d_in[8];
  const float* bemb = (const float*)d_in[9];
  const unsigned char* uprev = (const unsigned char*)d_in[10];
  float* out = (float*)d_out;
  float* ws  = (float*)d_ws;

  // zero the barrier control region (first 4 KiB) every call (inside graph)
  hipMemsetAsync(d_ws, 0, 4096, stream);

  void* args[] = {(void*)&x, (void*)&h0, (void*)&c0, (void*)&Wih0, (void*)&Wih1,
                  (void*)&Whh, (void*)&bih, (void*)&bhh, (void*)&Wemb, (void*)&bemb,
                  (void*)&uprev, (void*)&out, (void*)&ws};
  hipLaunchCooperativeKernel((void*)lstm_seq_kernel, dim3(NBLK), dim3(NTHR),
                             args, 0, stream);
}

// Round 17
// 25208.795 us; speedup vs baseline: 5.3280x; 5.3280x over previous
//
#include <hip/hip_runtime.h>

// Problem constants
#define Bc   64
#define Tc   512
#define NINc 256
#define Hc   512
#define NOUTc 256
#define NBLK 256
#define NTHR 1024
#define NWAVE 16
#define GSZ  32      // blocks per barrier group
#define NGRP 8       // groups

__device__ __forceinline__ float fsig(float x) { return 1.f / (1.f + expf(-x)); }

// ---- sc1 data plane: relaxed agent atomics bypass L1/L2, meet at MALL ----
__device__ __forceinline__ void stg1(float* p, float v) {
  __hip_atomic_store(p, v, __ATOMIC_RELAXED, __HIP_MEMORY_SCOPE_AGENT);
}
// 8-byte agent load (global_load_dwordx2 ... sc1) — layout [B][H] makes K contiguous
__device__ __forceinline__ float2 ldg2(const float* p) {
  unsigned long long u = __hip_atomic_load((const unsigned long long*)p,
                                           __ATOMIC_RELAXED, __HIP_MEMORY_SCOPE_AGENT);
  union { unsigned long long u; float2 f; } cvt; cvt.u = u;
  return cvt.f;
}

// ---- flat fence-free grid barrier (unchanged from R11/R15) ----
__device__ __forceinline__ void bar_arrive(unsigned* __restrict__ grp, int blk, unsigned ep) {
  asm volatile("s_waitcnt vmcnt(0)" ::: "memory");
  __syncthreads();
  if (threadIdx.x == 0)
    __hip_atomic_fetch_add(&grp[(blk >> 5) * 32], 1u,
                           __ATOMIC_RELAXED, __HIP_MEMORY_SCOPE_AGENT);
}
__device__ __forceinline__ void bar_wait(unsigned* __restrict__ grp, unsigned ep) {
  if (threadIdx.x < 64) {
    const unsigned tgt = ep * GSZ;
    for (;;) {
      bool ok = true;
      if (threadIdx.x < NGRP)
        ok = (__hip_atomic_load(&grp[threadIdx.x * 32], __ATOMIC_RELAXED,
                                __HIP_MEMORY_SCOPE_AGENT) >= tgt);
      if (__all(ok)) break;
      __builtin_amdgcn_s_sleep(1);
    }
  }
  __syncthreads();
  asm volatile("" ::: "memory");
}

// 8-term f32 fma group from chunk-local av[16] -> f32 accumulate (order == R15)
#define GRP8(W, base, kk, acc)                                   \
  {                                                              \
    float4 wa = *(const float4*)((W) + (base) + (kk));           \
    float4 wb = *(const float4*)((W) + (base) + (kk) + 4);       \
    float p =  av[(kk) + 0] * wa.x;                              \
    p = fmaf(av[(kk) + 1], wa.y, p);                             \
    p = fmaf(av[(kk) + 2], wa.z, p);                             \
    p = fmaf(av[(kk) + 3], wa.w, p);                             \
    p = fmaf(av[(kk) + 4], wb.x, p);                             \
    p = fmaf(av[(kk) + 5], wb.y, p);                             \
    p = fmaf(av[(kk) + 6], wb.z, p);                             \
    p = fmaf(av[(kk) + 7], wb.w, p);                             \
    (acc) += p;                                                  \
  }

// load 16 contiguous floats via 8 b64 sc1 loads into av[16]
#define LDCHUNK16(A, off)                                        \
  _Pragma("unroll")                                              \
  for (int k = 0; k < 8; ++k) {                                  \
    float2 v = ldg2((A) + (off) + k * 2);                        \
    av[k * 2] = v.x; av[k * 2 + 1] = v.y;                        \
  }

// ---- fused CD: contiguous h0 slice -> W_ih1:acc1 + W_hh0:acc0 ----
__device__ __forceinline__ void dot_cd32(const float* __restrict__ A,
                                         const float* __restrict__ W1, const int ws1,
                                         float* __restrict__ acc1,
                                         const float* __restrict__ W0, const int ws0,
                                         float* __restrict__ acc0) {
#pragma unroll 1
  for (int c = 0; c < 2; ++c) {
    float av[16];
    LDCHUNK16(A, c * 16);
#pragma unroll
    for (int kk = 0; kk < 16; kk += 8) {
#pragma unroll
      for (int r = 0; r < 8; ++r) GRP8(W1, r * ws1 + c * 16, kk, acc1[r]);
#pragma unroll
      for (int r = 0; r < 8; ++r) GRP8(W0, r * ws0 + c * 16, kk, acc0[r]);
    }
  }
}

// ---- fused EB: contiguous h1 slice -> W_hh1:acc1 + head row:hs ----
__device__ __forceinline__ void dot_eb32(const float* __restrict__ A,
                                         const float* __restrict__ W1, const int ws1,
                                         float* __restrict__ acc1,
                                         const float* __restrict__ Wh,
                                         float* __restrict__ hs) {
#pragma unroll 1
  for (int c = 0; c < 2; ++c) {
    float av[16];
    LDCHUNK16(A, c * 16);
#pragma unroll
    for (int kk = 0; kk < 16; kk += 8) {
#pragma unroll
      for (int r = 0; r < 8; ++r) GRP8(W1, r * ws1 + c * 16, kk, acc1[r]);
      GRP8(Wh, c * 16, kk, *hs);
    }
  }
}

// ---- single-acc contiguous sc1 dots ----
__device__ __forceinline__ void dot8_a32(const float* __restrict__ A,
                                         const float* __restrict__ W,
                                         const int wstride,
                                         float* __restrict__ acc) {
#pragma unroll 1
  for (int c = 0; c < 2; ++c) {
    float av[16];
    LDCHUNK16(A, c * 16);
#pragma unroll
    for (int kk = 0; kk < 16; kk += 8) {
#pragma unroll
      for (int r = 0; r < 8; ++r) GRP8(W, r * wstride + c * 16, kk, acc[r]);
    }
  }
}
__device__ __forceinline__ void dot8_a16(const float* __restrict__ A,
                                         const float* __restrict__ W,
                                         const int wstride,
                                         float* __restrict__ acc) {
  float av[16];
  LDCHUNK16(A, 0);
#pragma unroll
  for (int kk = 0; kk < 16; kk += 8) {
#pragma unroll
    for (int r = 0; r < 8; ++r) GRP8(W, r * wstride, kk, acc[r]);
  }
}

// A contiguous (raw x row, normal cached; read-only, never invalidated)
__device__ __forceinline__ void dot8_x16(const float* __restrict__ A,
                                         const float* __restrict__ W,
                                         const int wstride,
                                         float* __restrict__ acc) {
  float av[16];
#pragma unroll
  for (int kk = 0; kk < 16; kk += 4) {
    float4 v = *(const float4*)(A + kk);
    av[kk] = v.x; av[kk + 1] = v.y; av[kk + 2] = v.z; av[kk + 3] = v.w;
  }
#pragma unroll
  for (int kk = 0; kk < 16; kk += 8) {
#pragma unroll
    for (int r = 0; r < 8; ++r) GRP8(W, r * wstride, kk, acc[r]);
  }
}

__device__ __forceinline__ void write_plane(float* __restrict__ pb,
                                            const float* __restrict__ acc,
                                            int kg, int b) {
#pragma unroll
  for (int r = 0; r < 8; ++r) pb[(kg * 8 + r) * 64 + b] = acc[r];
}

__device__ __forceinline__ float sum_planes_f(const float* __restrict__ pb,
                                              int r, int b) {
  float s = 0.f;
#pragma unroll
  for (int p = 0; p < NWAVE; ++p) s += pb[(p * 8 + r) * 64 + b];
  return s;
}

extern "C" __global__ __launch_bounds__(NTHR, 4)
void lstm_seq_kernel(const float* __restrict__ x,      // [B,T,NIN]
                     const float* __restrict__ h0in,   // [L,B,H]
                     const float* __restrict__ c0in,   // [L,B,H]
                     const float* __restrict__ Wih0,   // [4H,NIN]
                     const float* __restrict__ Wih1,   // [4H,H]
                     const float* __restrict__ Whh,    // [L,4H,H]
                     const float* __restrict__ bih,    // [L,4H]
                     const float* __restrict__ bhh,    // [L,4H]
                     const float* __restrict__ Wemb,   // [NOUT,H]
                     const float* __restrict__ bemb,   // [NOUT]
                     const unsigned char* __restrict__ uprev, // [T] bool (or int32)
                     float* __restrict__ out,          // [B,T,NOUT]
                     float* __restrict__ ws) {
  __shared__ __align__(16) float wl0[8 * 768];    // [r][ W_ih0(256) | W_hh0(512) ]
  __shared__ __align__(16) float wl1[8 * 1024];   // [r][ W_ih1(512) | W_hh1(512) ]
  __shared__ __align__(16) float whd[512];        // W_emb row `blk`
  __shared__ __align__(16) float pbuf[NWAVE * 8 * 64];
  __shared__ __align__(16) float gbuf[8 * 64];    // nonlinearized gates
  __shared__ float biasesF[2][8];
  __shared__ float bembs;
  __shared__ int up_mode;

  const int tid = threadIdx.x;
  const int blk = blockIdx.x;
  const int b   = tid & 63;
  const int kg  = tid >> 6;   // wave index = K-group (0..15)
  const int j0  = blk * 2;

  // ---- workspace map (first 4 KiB control, zeroed by host memset) ----
  // h planes now [B][H]; outT now [B][NOUT] — per-thread K-slices contiguous
  unsigned* grp = (unsigned*)ws;               // 8 counters, 128B apart
  float* h0p  = ws + 1024;                     // [B][H]  layer-0 h plane
  float* h1p  = h0p + Hc * Bc;                 // [B][H]  layer-1 h plane
  float* outT = h1p + Hc * Bc;                 // [B][NOUT]

  // ---- detect use_prev dtype ----
  if (tid == 0) up_mode = 1;
  __syncthreads();
  {
    int bad = 0;
    for (int idx = tid; idx < Tc; idx += NTHR)
      if ((idx & 3) && uprev[idx]) bad = 1;
    if (bad) up_mode = 0;
  }

  // ---- load weights into LDS (cached reads; never invalidated) ----
  for (int r = 0; r < 8; ++r) {
    const int u = r >> 2, g = r & 3;
    const int row = g * Hc + (j0 + u);
    const float* sA = Wih0 + (size_t)row * NINc;
    const float* sB = Whh  + (size_t)row * Hc;
    const float* sC = Wih1 + (size_t)row * Hc;
    const float* sD = Whh  + (size_t)(4 * Hc) * Hc + (size_t)row * Hc;
    for (int i = tid; i < NINc; i += NTHR) wl0[r * 768 + i] = sA[i];
    for (int i = tid; i < Hc;   i += NTHR) wl0[r * 768 + NINc + i] = sB[i];
    for (int i = tid; i < Hc;   i += NTHR) wl1[r * 1024 + i] = sC[i];
    for (int i = tid; i < Hc;   i += NTHR) wl1[r * 1024 + Hc + i] = sD[i];
    if (tid == 0)
      biasesF[0][r] = (float)((double)bih[row] + (double)bhh[row]),
      biasesF[1][r] = (float)((double)bih[4 * Hc + row] + (double)bhh[4 * Hc + row]);
  }
  for (int i = tid; i < Hc; i += NTHR) whd[i] = Wemb[(size_t)blk * Hc + i];
  if (tid == 0) bembs = bemb[blk];

  // ---- init h planes [B][H] = straight copy of h0in[l]; sc1 stores ----
  for (int idx = blk * NTHR + tid; idx < 2 * Hc * Bc; idx += NBLK * NTHR) {
    const int l   = idx / (Hc * Bc);
    const int rem = idx - l * (Hc * Bc);
    stg1((l ? h1p : h0p) + rem, h0in[(size_t)l * Hc * Bc + rem]);
  }

  // ---- cell state (f64) in registers of threads 0..127 ----
  double c0r = 0.0, c1r = 0.0;
  const int cu = tid >> 6;
  if (tid < 128) {
    const int j = j0 + cu;
    c0r = (double)c0in[((size_t)0 * Bc + b) * Hc + j];
    c1r = (double)c0in[((size_t)1 * Bc + b) * Hc + j];
  }
  __syncthreads();
  const int upm = up_mode;
  const int* uprev32 = (const int*)uprev;
#define UPAT(tt) (upm ? (uprev32[tt] != 0) : (uprev[tt] != 0))

  unsigned ep = 0;
  bar_arrive(grp, blk, ++ep);   // publish h-plane init
  bar_wait(grp, ep);

  // ---- pre-loop: accL0 = W_ih0@x[0] + W_hh0@h0init; accL1 = W_hh1@h1init ----
  float accL0[8], accL1[8];
#pragma unroll
  for (int r = 0; r < 8; ++r) { accL0[r] = 0.f; accL1[r] = 0.f; }
  dot8_x16(x + ((size_t)b * Tc + 0) * NINc + kg * 16, &wl0[kg * 16], 768, accL0);
  dot8_a32(h0p + b * Hc + kg * 32, &wl0[NINc + kg * 32], 768, accL0);
  dot8_a32(h1p + b * Hc + kg * 32, &wl1[Hc + kg * 32], 1024, accL1);

  for (int t = 0; t < Tc; ++t) {
    const bool upn = (t + 1 < Tc) && UPAT(t + 1);

    // ---- 1. feedback part of L0[t] (only when scheduled sampling) ----
    if (t > 0 && UPAT(t))
      dot8_a16(outT + b * NOUTc + kg * 16, &wl0[kg * 16], 768, accL0);

    // ---- 2. L0 cell: distributed gates (512 thr) + finish (128 thr) ----
    write_plane(pbuf, accL0, kg, b);
    __syncthreads();
    if (tid < 512) {
      const int r = kg & 7;   // kg<8 for tid<512
      float s = sum_planes_f(pbuf, r, b) + biasesF[0][r];
      gbuf[r * 64 + b] = ((r & 3) == 2) ? tanhf(s) : fsig(s);
    }
    __syncthreads();
    if (tid < 128) {
      float si = gbuf[(cu * 4 + 0) * 64 + b];
      float sf = gbuf[(cu * 4 + 1) * 64 + b];
      float sg = gbuf[(cu * 4 + 2) * 64 + b];
      float so = gbuf[(cu * 4 + 3) * 64 + b];
      double cn = (double)sf * c0r + (double)(si * sg);
      c0r = cn;
      stg1(&h0p[b * Hc + (j0 + cu)], so * tanhf((float)cn));
    }
#pragma unroll
    for (int r = 0; r < 8; ++r) accL0[r] = 0.f;
    bar_arrive(grp, blk, ++ep);

    // ---- 3. hidden behind bar1: x[t+1] part of L0[t+1] (cached) ----
    if (t + 1 < Tc && !upn)
      dot8_x16(x + ((size_t)b * Tc + (t + 1)) * NINc + kg * 16, &wl0[kg * 16], 768, accL0);

    bar_wait(grp, ep);   // h0[t] visible

    // ---- 5. fused CD: one h0[t] slice -> accL1 (W_ih1) + accL0 (W_hh0, t+1) ----
    dot_cd32(h0p + b * Hc + kg * 32,
             &wl1[kg * 32], 1024, accL1,
             &wl0[NINc + kg * 32], 768, accL0);

    // ---- 6. L1 cell: distributed gates + finish, publish h1[t] ----
    write_plane(pbuf, accL1, kg, b);
    __syncthreads();
    if (tid < 512) {
      const int r = kg & 7;
      float s = sum_planes_f(pbuf, r, b) + biasesF[1][r];
      gbuf[r * 64 + b] = ((r & 3) == 2) ? tanhf(s) : fsig(s);
    }
    __syncthreads();
    if (tid < 128) {
      float si = gbuf[(cu * 4 + 0) * 64 + b];
      float sf = gbuf[(cu * 4 + 1) * 64 + b];
      float sg = gbuf[(cu * 4 + 2) * 64 + b];
      float so = gbuf[(cu * 4 + 3) * 64 + b];
      double cn = (double)sf * c1r + (double)(si * sg);
      c1r = cn;
      stg1(&h1p[b * Hc + (j0 + cu)], so * tanhf((float)cn));
    }
#pragma unroll
    for (int r = 0; r < 8; ++r) accL1[r] = 0.f;
    bar_arrive(grp, blk, ++ep);
    bar_wait(grp, ep);   // h1[t] visible

    // ---- 8. fused EB: one h1[t] slice -> head partial + accL1 (W_hh1, t+1) ----
    {
      float hs = 0.f;
      dot_eb32(h1p + b * Hc + kg * 32,
               &wl1[Hc + kg * 32], 1024, accL1,
               &whd[kg * 32], &hs);
      pbuf[kg * 64 + b] = hs;
    }
    __syncthreads();

    // ---- 9. head finish; out + feedback publish ----
    if (tid < 64) {
      float s = bembs;
#pragma unroll
      for (int pl = 0; pl < NWAVE; ++pl) s += pbuf[pl * 64 + b];
      float o = tanhf(s);
      stg1(&outT[b * NOUTc + blk], o);                 // feedback buffer [B][NOUT]
      out[((size_t)b * Tc + t) * NOUTc + blk] = o;     // final output [B,T,NOUT]
    }
    if (upn) {
      bar_arrive(grp, blk, ++ep);                      // publish out[t]
      bar_wait(grp, ep);
    } else if (t + 1 < Tc) {
      __syncthreads();                                 // pbuf reuse guard
    }
  }
}

extern "C" void kernel_launch(void* const* d_in, const int* in_sizes, int n_in,
                              void* d_out, int out_size, void* d_ws, size_t ws_size,
                              hipStream_t stream) {
  const float* x    = (const float*)d_in[0];
  const float* h0   = (const float*)d_in[1];
  const float* c0   = (const float*)d_in[2];
  const float* Wih0 = (const float*)d_in[3];
  const float* Wih1 = (const float*)d_in[4];
  const float* Whh  = (const float*)d_in[5];
  const float* bih  = (const float*)d_in[6];
  const float* bhh  = (const float*)d_in[7];
  const float* Wemb = (const float*)d_in[8];
  const float* bemb = (const float*)d_in[9];
  const unsigned char* uprev = (const unsigned char*)d_in[10];
  float* out = (float*)d_out;
  float* ws  = (float*)d_ws;

  // zero the barrier control region (first 4 KiB) every call (inside graph)
  hipMemsetAsync(d_ws, 0, 4096, stream);

  void* args[] = {(void*)&x, (void*)&h0, (void*)&c0, (void*)&Wih0, (void*)&Wih1,
                  (void*)&Whh, (void*)&bih, (void*)&bhh, (void*)&Wemb, (void*)&bemb,
                  (void*)&uprev, (void*)&out, (void*)&ws};
  hipLaunchCooperativeKernel((void*)lstm_seq_kernel, dim3(NBLK), dim3(NTHR),
                             args, 0, stream);
}

// Round 18
// 10880.770 us; speedup vs baseline: 12.3441x; 2.3168x over previous
//
#include <hip/hip_runtime.h>

// Problem constants
#define Bc   64
#define Tc   512
#define NINc 256
#define Hc   512
#define NOUTc 256
#define NBLK 256
#define NTHR 1024
#define NWAVE 16
#define GSZ  32      // blocks per barrier group
#define NGRP 8       // groups

__device__ __forceinline__ float fsig(float x) { return 1.f / (1.f + expf(-x)); }

// ---- sc1 data plane: relaxed agent atomics bypass L1/L2, meet at MALL ----
__device__ __forceinline__ float ldg1(const float* p) {
  return __hip_atomic_load(p, __ATOMIC_RELAXED, __HIP_MEMORY_SCOPE_AGENT);
}
__device__ __forceinline__ void stg1(float* p, float v) {
  __hip_atomic_store(p, v, __ATOMIC_RELAXED, __HIP_MEMORY_SCOPE_AGENT);
}

// ---- flat fence-free grid barrier (R11/R15-proven) ----
__device__ __forceinline__ void bar_arrive(unsigned* __restrict__ grp, int blk, unsigned ep) {
  asm volatile("s_waitcnt vmcnt(0)" ::: "memory");
  __syncthreads();
  if (threadIdx.x == 0)
    __hip_atomic_fetch_add(&grp[(blk >> 5) * 32], 1u,
                           __ATOMIC_RELAXED, __HIP_MEMORY_SCOPE_AGENT);
}
__device__ __forceinline__ void bar_wait(unsigned* __restrict__ grp, unsigned ep) {
  if (threadIdx.x < 64) {
    const unsigned tgt = ep * GSZ;
    for (;;) {
      bool ok = true;
      if (threadIdx.x < NGRP)
        ok = (__hip_atomic_load(&grp[threadIdx.x * 32], __ATOMIC_RELAXED,
                                __HIP_MEMORY_SCOPE_AGENT) >= tgt);
      if (__all(ok)) break;
      __builtin_amdgcn_s_sleep(1);
    }
  }
  __syncthreads();
  asm volatile("" ::: "memory");
}

// 8-term f32 fma group -> f32 accumulate (av indexed within current chunk)
#define GRP8(W, base, kk, acc)                                   \
  {                                                              \
    float4 wa = *(const float4*)((W) + (base) + (kk));           \
    float4 wb = *(const float4*)((W) + (base) + (kk) + 4);       \
    float p =  av[(kk) + 0] * wa.x;                              \
    p = fmaf(av[(kk) + 1], wa.y, p);                             \
    p = fmaf(av[(kk) + 2], wa.z, p);                             \
    p = fmaf(av[(kk) + 3], wa.w, p);                             \
    p = fmaf(av[(kk) + 4], wb.x, p);                             \
    p = fmaf(av[(kk) + 5], wb.y, p);                             \
    p = fmaf(av[(kk) + 6], wb.z, p);                             \
    p = fmaf(av[(kk) + 7], wb.w, p);                             \
    (acc) += p;                                                  \
  }

// ---- fused CD: one sc1 h0 stream (16-deep chunks) -> W_ih1:acc1 + W_hh0:acc0 ----
__device__ __forceinline__ void dot_cd32(const float* __restrict__ A,
                                         const float* __restrict__ W1, const int ws1,
                                         float* __restrict__ acc1,
                                         const float* __restrict__ W0, const int ws0,
                                         float* __restrict__ acc0) {
#pragma unroll 1
  for (int c = 0; c < 2; ++c) {
    float av[16];
#pragma unroll
    for (int k = 0; k < 16; ++k) av[k] = ldg1(A + (c * 16 + k) * Bc);
#pragma unroll
    for (int kk = 0; kk < 16; kk += 8) {
#pragma unroll
      for (int r = 0; r < 8; ++r) GRP8(W1, r * ws1 + c * 16, kk, acc1[r]);
#pragma unroll
      for (int r = 0; r < 8; ++r) GRP8(W0, r * ws0 + c * 16, kk, acc0[r]);
    }
  }
}

// ---- fused EB: one sc1 h1 stream -> W_hh1:acc1 + head row:hs ----
__device__ __forceinline__ void dot_eb32(const float* __restrict__ A,
                                         const float* __restrict__ W1, const int ws1,
                                         float* __restrict__ acc1,
                                         const float* __restrict__ Wh,
                                         float* __restrict__ hs) {
#pragma unroll 1
  for (int c = 0; c < 2; ++c) {
    float av[16];
#pragma unroll
    for (int k = 0; k < 16; ++k) av[k] = ldg1(A + (c * 16 + k) * Bc);
#pragma unroll
    for (int kk = 0; kk < 16; kk += 8) {
#pragma unroll
      for (int r = 0; r < 8; ++r) GRP8(W1, r * ws1 + c * 16, kk, acc1[r]);
      GRP8(Wh, c * 16, kk, *hs);
    }
  }
}

// ---- single-acc sc1 dots ----
__device__ __forceinline__ void dot8_a32(const float* __restrict__ A,
                                         const float* __restrict__ W,
                                         const int wstride,
                                         float* __restrict__ acc) {
#pragma unroll 1
  for (int c = 0; c < 2; ++c) {
    float av[16];
#pragma unroll
    for (int k = 0; k < 16; ++k) av[k] = ldg1(A + (c * 16 + k) * Bc);
#pragma unroll
    for (int kk = 0; kk < 16; kk += 8) {
#pragma unroll
      for (int r = 0; r < 8; ++r) GRP8(W, r * wstride + c * 16, kk, acc[r]);
    }
  }
}
__device__ __forceinline__ void dot8_a16(const float* __restrict__ A,
                                         const float* __restrict__ W,
                                         const int wstride,
                                         float* __restrict__ acc) {
  float av[16];
#pragma unroll
  for (int k = 0; k < 16; ++k) av[k] = ldg1(A + k * Bc);
#pragma unroll
  for (int kk = 0; kk < 16; kk += 8) {
#pragma unroll
    for (int r = 0; r < 8; ++r) GRP8(W, r * wstride, kk, acc[r]);
  }
}

// A contiguous (raw x row, normal cached; read-only, never invalidated)
__device__ __forceinline__ void dot8_x16(const float* __restrict__ A,
                                         const float* __restrict__ W,
                                         const int wstride,
                                         float* __restrict__ acc) {
  float av[16];
#pragma unroll
  for (int kk = 0; kk < 16; kk += 4) {
    float4 v = *(const float4*)(A + kk);
    av[kk] = v.x; av[kk + 1] = v.y; av[kk + 2] = v.z; av[kk + 3] = v.w;
  }
#pragma unroll
  for (int kk = 0; kk < 16; kk += 8) {
#pragma unroll
    for (int r = 0; r < 8; ++r) GRP8(W, r * wstride, kk, acc[r]);
  }
}

__device__ __forceinline__ void write_plane(float* __restrict__ pb,
                                            const float* __restrict__ acc,
                                            int kg, int b) {
#pragma unroll
  for (int r = 0; r < 8; ++r) pb[(kg * 8 + r) * 64 + b] = acc[r];
}

__device__ __forceinline__ float sum_planes_f(const float* __restrict__ pb,
                                              int r, int b) {
  float s = 0.f;
#pragma unroll
  for (int p = 0; p < NWAVE; ++p) s += pb[(p * 8 + r) * 64 + b];
  return s;
}

extern "C" __global__ __launch_bounds__(NTHR, 4)
void lstm_seq_kernel(const float* __restrict__ x,      // [B,T,NIN]
                     const float* __restrict__ h0in,   // [L,B,H]
                     const float* __restrict__ c0in,   // [L,B,H]
                     const float* __restrict__ Wih0,   // [4H,NIN]
                     const float* __restrict__ Wih1,   // [4H,H]
                     const float* __restrict__ Whh,    // [L,4H,H]
                     const float* __restrict__ bih,    // [L,4H]
                     const float* __restrict__ bhh,    // [L,4H]
                     const float* __restrict__ Wemb,   // [NOUT,H]
                     const float* __restrict__ bemb,   // [NOUT]
                     const unsigned char* __restrict__ uprev, // [T] bool (or int32)
                     float* __restrict__ out,          // [B,T,NOUT]
                     float* __restrict__ ws) {
  __shared__ __align__(16) float wl0[8 * 768];    // [r][ W_ih0(256) | W_hh0(512) ]
  __shared__ __align__(16) float wl1[8 * 1024];   // [r][ W_ih1(512) | W_hh1(512) ]
  __shared__ __align__(16) float whd[512];        // W_emb row `blk`
  __shared__ __align__(16) float pbuf[NWAVE * 8 * 64];
  __shared__ __align__(16) float gbuf[8 * 64];    // nonlinearized gates
  __shared__ float biasesF[2][8];
  __shared__ float bembs;
  __shared__ int up_mode;

  const int tid = threadIdx.x;
  const int blk = blockIdx.x;
  const int b   = tid & 63;
  const int kg  = tid >> 6;   // wave index = K-group (0..15)
  const int j0  = blk * 2;

  // ---- workspace map (first 4 KiB control, zeroed by host memset) ----
  unsigned* grp = (unsigned*)ws;               // 8 counters, 128B apart
  float* h0p  = ws + 1024;                     // [H][B]  layer-0 h plane
  float* h1p  = h0p + Hc * Bc;                 // [H][B]  layer-1 h plane
  float* outT = h1p + Hc * Bc;                 // [NOUT][B]

  // ---- detect use_prev dtype ----
  if (tid == 0) up_mode = 1;
  __syncthreads();
  {
    int bad = 0;
    for (int idx = tid; idx < Tc; idx += NTHR)
      if ((idx & 3) && uprev[idx]) bad = 1;
    if (bad) up_mode = 0;
  }

  // ---- load weights into LDS (cached reads; never invalidated) ----
  for (int r = 0; r < 8; ++r) {
    const int u = r >> 2, g = r & 3;
    const int row = g * Hc + (j0 + u);
    const float* sA = Wih0 + (size_t)row * NINc;
    const float* sB = Whh  + (size_t)row * Hc;
    const float* sC = Wih1 + (size_t)row * Hc;
    const float* sD = Whh  + (size_t)(4 * Hc) * Hc + (size_t)row * Hc;
    for (int i = tid; i < NINc; i += NTHR) wl0[r * 768 + i] = sA[i];
    for (int i = tid; i < Hc;   i += NTHR) wl0[r * 768 + NINc + i] = sB[i];
    for (int i = tid; i < Hc;   i += NTHR) wl1[r * 1024 + i] = sC[i];
    for (int i = tid; i < Hc;   i += NTHR) wl1[r * 1024 + Hc + i] = sD[i];
    if (tid == 0)
      biasesF[0][r] = (float)((double)bih[row] + (double)bhh[row]),
      biasesF[1][r] = (float)((double)bih[4 * Hc + row] + (double)bhh[4 * Hc + row]);
  }
  for (int i = tid; i < Hc; i += NTHR) whd[i] = Wemb[(size_t)blk * Hc + i];
  if (tid == 0) bembs = bemb[blk];

  // ---- init h planes transposed to [H][B]; sc1 stores ----
  for (int idx = blk * NTHR + tid; idx < 2 * Hc * Bc; idx += NBLK * NTHR) {
    const int l   = idx / (Hc * Bc);
    const int rem = idx - l * (Hc * Bc);
    const int j   = rem >> 6;
    const int bb  = rem & 63;
    stg1((l ? h1p : h0p) + rem, h0in[((size_t)l * Bc + bb) * Hc + j]);
  }

  // ---- cell state (f64) in registers of threads 0..127 ----
  double c0r = 0.0, c1r = 0.0;
  const int cu = tid >> 6;
  if (tid < 128) {
    const int j = j0 + cu;
    c0r = (double)c0in[((size_t)0 * Bc + b) * Hc + j];
    c1r = (double)c0in[((size_t)1 * Bc + b) * Hc + j];
  }
  __syncthreads();
  const int upm = up_mode;
  const int* uprev32 = (const int*)uprev;
#define UPAT(tt) (upm ? (uprev32[tt] != 0) : (uprev[tt] != 0))

  unsigned ep = 0;
  bar_arrive(grp, blk, ++ep);   // publish h-plane init
  bar_wait(grp, ep);

  // ---- pre-loop: accL0 = W_ih0@x[0] + W_hh0@h0init; accL1 = W_hh1@h1init ----
  float accL0[8], accL1[8];
#pragma unroll
  for (int r = 0; r < 8; ++r) { accL0[r] = 0.f; accL1[r] = 0.f; }
  dot8_x16(x + ((size_t)b * Tc + 0) * NINc + kg * 16, &wl0[kg * 16], 768, accL0);
  dot8_a32(h0p + (kg * 32) * Bc + b, &wl0[NINc + kg * 32], 768, accL0);
  dot8_a32(h1p + (kg * 32) * Bc + b, &wl1[Hc + kg * 32], 1024, accL1);

  for (int t = 0; t < Tc; ++t) {
    const bool upn = (t + 1 < Tc) && UPAT(t + 1);

    // ---- 1. feedback part of L0[t] (only when scheduled sampling) ----
    if (t > 0 && UPAT(t))
      dot8_a16(outT + (kg * 16) * Bc + b, &wl0[kg * 16], 768, accL0);

    // ---- 2. L0 cell: distributed gates (512 thr) + finish (128 thr) ----
    write_plane(pbuf, accL0, kg, b);
    __syncthreads();
    if (tid < 512) {
      const int r = kg & 7;   // kg<8 for tid<512
      float s = sum_planes_f(pbuf, r, b) + biasesF[0][r];
      gbuf[r * 64 + b] = ((r & 3) == 2) ? tanhf(s) : fsig(s);
    }
    __syncthreads();
    if (tid < 128) {
      float si = gbuf[(cu * 4 + 0) * 64 + b];
      float sf = gbuf[(cu * 4 + 1) * 64 + b];
      float sg = gbuf[(cu * 4 + 2) * 64 + b];
      float so = gbuf[(cu * 4 + 3) * 64 + b];
      double cn = (double)sf * c0r + (double)(si * sg);
      c0r = cn;
      stg1(&h0p[(j0 + cu) * Bc + b], so * tanhf((float)cn));
    }
#pragma unroll
    for (int r = 0; r < 8; ++r) accL0[r] = 0.f;
    bar_arrive(grp, blk, ++ep);

    // ---- 3. hidden behind bar1: x[t+1] part of L0[t+1] (cached) ----
    if (t + 1 < Tc && !upn)
      dot8_x16(x + ((size_t)b * Tc + (t + 1)) * NINc + kg * 16, &wl0[kg * 16], 768, accL0);

    bar_wait(grp, ep);   // h0[t] visible

    // ---- 5. fused CD: one h0[t] stream -> accL1 (W_ih1) + accL0 (W_hh0, t+1) ----
    dot_cd32(h0p + (kg * 32) * Bc + b,
             &wl1[kg * 32], 1024, accL1,
             &wl0[NINc + kg * 32], 768, accL0);

    // ---- 6. L1 cell: distributed gates + finish, publish h1[t] ----
    write_plane(pbuf, accL1, kg, b);
    __syncthreads();
    if (tid < 512) {
      const int r = kg & 7;
      float s = sum_planes_f(pbuf, r, b) + biasesF[1][r];
      gbuf[r * 64 + b] = ((r & 3) == 2) ? tanhf(s) : fsig(s);
    }
    __syncthreads();
    if (tid < 128) {
      float si = gbuf[(cu * 4 + 0) * 64 + b];
      float sf = gbuf[(cu * 4 + 1) * 64 + b];
      float sg = gbuf[(cu * 4 + 2) * 64 + b];
      float so = gbuf[(cu * 4 + 3) * 64 + b];
      double cn = (double)sf * c1r + (double)(si * sg);
      c1r = cn;
      stg1(&h1p[(j0 + cu) * Bc + b], so * tanhf((float)cn));
    }
#pragma unroll
    for (int r = 0; r < 8; ++r) accL1[r] = 0.f;
    bar_arrive(grp, blk, ++ep);
    bar_wait(grp, ep);   // h1[t] visible

    // ---- 8. fused EB: one h1[t] stream -> head partial + accL1 (W_hh1, t+1) ----
    {
      float hs = 0.f;
      dot_eb32(h1p + (kg * 32) * Bc + b,
               &wl1[Hc + kg * 32], 1024, accL1,
               &whd[kg * 32], &hs);
      pbuf[kg * 64 + b] = hs;
    }
    __syncthreads();

    // ---- 9. head finish; out + feedback publish ----
    if (tid < 64) {
      float s = bembs;
#pragma unroll
      for (int pl = 0; pl < NWAVE; ++pl) s += pbuf[pl * 64 + b];
      float o = tanhf(s);
      stg1(&outT[blk * Bc + b], o);                    // feedback buffer [NOUT][B]
      out[((size_t)b * Tc + t) * NOUTc + blk] = o;     // final output [B,T,NOUT]
    }
    if (upn) {
      bar_arrive(grp, blk, ++ep);                      // publish out[t]
      bar_wait(grp, ep);
    } else if (t + 1 < Tc) {
      __syncthreads();                                 // pbuf reuse guard
    }
  }
}

extern "C" void kernel_launch(void* const* d_in, const int* in_sizes, int n_in,
                              void* d_out, int out_size, void* d_ws, size_t ws_size,
                              hipStream_t stream) {
  const float* x    = (const float*)d_in[0];
  const float* h0   = (const float*)d_in[1];
  const float* c0   = (const float*)d_in[2];
  const float* Wih0 = (const float*)d_in[3];
  const float* Wih1 = (const float*)d_in[4];
  const float* Whh  = (const float*)d_in[5];
  const float* bih  = (const float*)d_in[6];
  const float* bhh  = (const float*)d_in[7];
  const float* Wemb = (const float*)d_in[8];
  const float* bemb = (const float*)d_in[9];
  const unsigned char* uprev = (const unsigned char*)d_in[10];
  float* out = (float*)d_out;
  float* ws  = (float*)d_ws;

  // zero the barrier control region (first 4 KiB) every call (inside graph)
  hipMemsetAsync(d_ws, 0, 4096, stream);

  void* args[] = {(void*)&x, (void*)&h0, (void*)&c0, (void*)&Wih0, (void*)&Wih1,
                  (void*)&Whh, (void*)&bih, (void*)&bhh, (void*)&Wemb, (void*)&bemb,
                  (void*)&uprev, (void*)&out, (void*)&ws};
  hipLaunchCooperativeKernel((void*)lstm_seq_kernel, dim3(NBLK), dim3(NTHR),
                             args, 0, stream);
}

// Round 19
// 8489.631 us; speedup vs baseline: 15.8208x; 1.2817x over previous
//
#include <hip/hip_runtime.h>

// Problem constants
#define Bc   64
#define Tc   512
#define NINc 256
#define Hc   512
#define NOUTc 256
#define NBLK 256
#define NTHR 1024
#define NWAVE 16
#define NCTR 64      // barrier counters (128B apart)
#define GSZ2 4       // blocks per counter

__device__ __forceinline__ float fsig(float x) { return 1.f / (1.f + expf(-x)); }

// ---- sc1 data plane: relaxed agent atomics bypass L1/L2, meet at MALL ----
__device__ __forceinline__ float ldg1(const float* p) {
  return __hip_atomic_load(p, __ATOMIC_RELAXED, __HIP_MEMORY_SCOPE_AGENT);
}
__device__ __forceinline__ void stg1(float* p, float v) {
  __hip_atomic_store(p, v, __ATOMIC_RELAXED, __HIP_MEMORY_SCOPE_AGENT);
}

// ---- flat fence-free grid barrier, WIDE FAN: 64 counters x 4 RMWs ----
// arrival serialization drops 32 -> 4 RMWs per line (~0.4us vs ~3.2us).
__device__ __forceinline__ void bar_arrive(unsigned* __restrict__ grp, int blk, unsigned ep) {
  asm volatile("s_waitcnt vmcnt(0)" ::: "memory");
  __syncthreads();
  if (threadIdx.x == 0)
    __hip_atomic_fetch_add(&grp[(blk & (NCTR - 1)) * 32], 1u,
                           __ATOMIC_RELAXED, __HIP_MEMORY_SCOPE_AGENT);
}
// wait: wave 0's 64 lanes poll the 64 counters in parallel.
__device__ __forceinline__ void bar_wait(unsigned* __restrict__ grp, unsigned ep) {
  if (threadIdx.x < 64) {
    const unsigned tgt = ep * GSZ2;
    for (;;) {
      bool ok = (__hip_atomic_load(&grp[threadIdx.x * 32], __ATOMIC_RELAXED,
                                   __HIP_MEMORY_SCOPE_AGENT) >= tgt);
      if (__all(ok)) break;
      __builtin_amdgcn_s_sleep(1);
    }
  }
  __syncthreads();
  asm volatile("" ::: "memory");
}

// 8-term f32 fma group -> f32 accumulate (av indexed within current chunk)
#define GRP8(W, base, kk, acc)                                   \
  {                                                              \
    float4 wa = *(const float4*)((W) + (base) + (kk));           \
    float4 wb = *(const float4*)((W) + (base) + (kk) + 4);       \
    float p =  av[(kk) + 0] * wa.x;                              \
    p = fmaf(av[(kk) + 1], wa.y, p);                             \
    p = fmaf(av[(kk) + 2], wa.z, p);                             \
    p = fmaf(av[(kk) + 3], wa.w, p);                             \
    p = fmaf(av[(kk) + 4], wb.x, p);                             \
    p = fmaf(av[(kk) + 5], wb.y, p);                             \
    p = fmaf(av[(kk) + 6], wb.z, p);                             \
    p = fmaf(av[(kk) + 7], wb.w, p);                             \
    (acc) += p;                                                  \
  }

// ---- fused CD: one sc1 h0 stream (16-deep chunks) -> W_ih1:acc1 + W_hh0:acc0 ----
__device__ __forceinline__ void dot_cd32(const float* __restrict__ A,
                                         const float* __restrict__ W1, const int ws1,
                                         float* __restrict__ acc1,
                                         const float* __restrict__ W0, const int ws0,
                                         float* __restrict__ acc0) {
#pragma unroll 1
  for (int c = 0; c < 2; ++c) {
    float av[16];
#pragma unroll
    for (int k = 0; k < 16; ++k) av[k] = ldg1(A + (c * 16 + k) * Bc);
#pragma unroll
    for (int kk = 0; kk < 16; kk += 8) {
#pragma unroll
      for (int r = 0; r < 8; ++r) GRP8(W1, r * ws1 + c * 16, kk, acc1[r]);
#pragma unroll
      for (int r = 0; r < 8; ++r) GRP8(W0, r * ws0 + c * 16, kk, acc0[r]);
    }
  }
}

// ---- fused EB: one sc1 h1 stream -> W_hh1:acc1 + head row:hs ----
__device__ __forceinline__ void dot_eb32(const float* __restrict__ A,
                                         const float* __restrict__ W1, const int ws1,
                                         float* __restrict__ acc1,
                                         const float* __restrict__ Wh,
                                         float* __restrict__ hs) {
#pragma unroll 1
  for (int c = 0; c < 2; ++c) {
    float av[16];
#pragma unroll
    for (int k = 0; k < 16; ++k) av[k] = ldg1(A + (c * 16 + k) * Bc);
#pragma unroll
    for (int kk = 0; kk < 16; kk += 8) {
#pragma unroll
      for (int r = 0; r < 8; ++r) GRP8(W1, r * ws1 + c * 16, kk, acc1[r]);
      GRP8(Wh, c * 16, kk, *hs);
    }
  }
}

// ---- single-acc sc1 dots ----
__device__ __forceinline__ void dot8_a32(const float* __restrict__ A,
                                         const float* __restrict__ W,
                                         const int wstride,
                                         float* __restrict__ acc) {
#pragma unroll 1
  for (int c = 0; c < 2; ++c) {
    float av[16];
#pragma unroll
    for (int k = 0; k < 16; ++k) av[k] = ldg1(A + (c * 16 + k) * Bc);
#pragma unroll
    for (int kk = 0; kk < 16; kk += 8) {
#pragma unroll
      for (int r = 0; r < 8; ++r) GRP8(W, r * wstride + c * 16, kk, acc[r]);
    }
  }
}
__device__ __forceinline__ void dot8_a16(const float* __restrict__ A,
                                         const float* __restrict__ W,
                                         const int wstride,
                                         float* __restrict__ acc) {
  float av[16];
#pragma unroll
  for (int k = 0; k < 16; ++k) av[k] = ldg1(A + k * Bc);
#pragma unroll
  for (int kk = 0; kk < 16; kk += 8) {
#pragma unroll
    for (int r = 0; r < 8; ++r) GRP8(W, r * wstride, kk, acc[r]);
  }
}

// A contiguous (raw x row, normal cached; read-only, never invalidated)
__device__ __forceinline__ void dot8_x16(const float* __restrict__ A,
                                         const float* __restrict__ W,
                                         const int wstride,
                                         float* __restrict__ acc) {
  float av[16];
#pragma unroll
  for (int kk = 0; kk < 16; kk += 4) {
    float4 v = *(const float4*)(A + kk);
    av[kk] = v.x; av[kk + 1] = v.y; av[kk + 2] = v.z; av[kk + 3] = v.w;
  }
#pragma unroll
  for (int kk = 0; kk < 16; kk += 8) {
#pragma unroll
    for (int r = 0; r < 8; ++r) GRP8(W, r * wstride, kk, acc[r]);
  }
}

__device__ __forceinline__ void write_plane(float* __restrict__ pb,
                                            const float* __restrict__ acc,
                                            int kg, int b) {
#pragma unroll
  for (int r = 0; r < 8; ++r) pb[(kg * 8 + r) * 64 + b] = acc[r];
}

__device__ __forceinline__ float sum_planes_f(const float* __restrict__ pb,
                                              int r, int b) {
  float s = 0.f;
#pragma unroll
  for (int p = 0; p < NWAVE; ++p) s += pb[(p * 8 + r) * 64 + b];
  return s;
}

extern "C" __global__ __launch_bounds__(NTHR, 4)
void lstm_seq_kernel(const float* __restrict__ x,      // [B,T,NIN]
                     const float* __restrict__ h0in,   // [L,B,H]
                     const float* __restrict__ c0in,   // [L,B,H]
                     const float* __restrict__ Wih0,   // [4H,NIN]
                     const float* __restrict__ Wih1,   // [4H,H]
                     const float* __restrict__ Whh,    // [L,4H,H]
                     const float* __restrict__ bih,    // [L,4H]
                     const float* __restrict__ bhh,    // [L,4H]
                     const float* __restrict__ Wemb,   // [NOUT,H]
                     const float* __restrict__ bemb,   // [NOUT]
                     const unsigned char* __restrict__ uprev, // [T] bool (or int32)
                     float* __restrict__ out,          // [B,T,NOUT]
                     float* __restrict__ ws) {
  __shared__ __align__(16) float wl0[8 * 768];    // [r][ W_ih0(256) | W_hh0(512) ]
  __shared__ __align__(16) float wl1[8 * 1024];   // [r][ W_ih1(512) | W_hh1(512) ]
  __shared__ __align__(16) float whd[512];        // W_emb row `blk`
  __shared__ __align__(16) float pbuf[NWAVE * 8 * 64];
  __shared__ __align__(16) float gbuf[8 * 64];    // nonlinearized gates
  __shared__ float biasesF[2][8];
  __shared__ float bembs;
  __shared__ int up_mode;

  const int tid = threadIdx.x;
  const int blk = blockIdx.x;
  const int b   = tid & 63;
  const int kg  = tid >> 6;   // wave index = K-group (0..15)
  const int j0  = blk * 2;

  // ---- workspace map (first 16 KiB control, zeroed by host memset) ----
  unsigned* grp = (unsigned*)ws;               // 64 counters, 128B apart (8KB)
  float* h0p  = ws + 4096;                     // [H][B]  layer-0 h plane
  float* h1p  = h0p + Hc * Bc;                 // [H][B]  layer-1 h plane
  float* outT = h1p + Hc * Bc;                 // [NOUT][B]

  // ---- detect use_prev dtype ----
  if (tid == 0) up_mode = 1;
  __syncthreads();
  {
    int bad = 0;
    for (int idx = tid; idx < Tc; idx += NTHR)
      if ((idx & 3) && uprev[idx]) bad = 1;
    if (bad) up_mode = 0;
  }

  // ---- load weights into LDS (cached reads; never invalidated) ----
  for (int r = 0; r < 8; ++r) {
    const int u = r >> 2, g = r & 3;
    const int row = g * Hc + (j0 + u);
    const float* sA = Wih0 + (size_t)row * NINc;
    const float* sB = Whh  + (size_t)row * Hc;
    const float* sC = Wih1 + (size_t)row * Hc;
    const float* sD = Whh  + (size_t)(4 * Hc) * Hc + (size_t)row * Hc;
    for (int i = tid; i < NINc; i += NTHR) wl0[r * 768 + i] = sA[i];
    for (int i = tid; i < Hc;   i += NTHR) wl0[r * 768 + NINc + i] = sB[i];
    for (int i = tid; i < Hc;   i += NTHR) wl1[r * 1024 + i] = sC[i];
    for (int i = tid; i < Hc;   i += NTHR) wl1[r * 1024 + Hc + i] = sD[i];
    if (tid == 0)
      biasesF[0][r] = (float)((double)bih[row] + (double)bhh[row]),
      biasesF[1][r] = (float)((double)bih[4 * Hc + row] + (double)bhh[4 * Hc + row]);
  }
  for (int i = tid; i < Hc; i += NTHR) whd[i] = Wemb[(size_t)blk * Hc + i];
  if (tid == 0) bembs = bemb[blk];

  // ---- init h planes transposed to [H][B]; sc1 stores ----
  for (int idx = blk * NTHR + tid; idx < 2 * Hc * Bc; idx += NBLK * NTHR) {
    const int l   = idx / (Hc * Bc);
    const int rem = idx - l * (Hc * Bc);
    const int j   = rem >> 6;
    const int bb  = rem & 63;
    stg1((l ? h1p : h0p) + rem, h0in[((size_t)l * Bc + bb) * Hc + j]);
  }

  // ---- cell state (f64) in registers of threads 0..127 ----
  double c0r = 0.0, c1r = 0.0;
  const int cu = tid >> 6;
  if (tid < 128) {
    const int j = j0 + cu;
    c0r = (double)c0in[((size_t)0 * Bc + b) * Hc + j];
    c1r = (double)c0in[((size_t)1 * Bc + b) * Hc + j];
  }
  __syncthreads();
  const int upm = up_mode;
  const int* uprev32 = (const int*)uprev;
#define UPAT(tt) (upm ? (uprev32[tt] != 0) : (uprev[tt] != 0))

  unsigned ep = 0;
  bar_arrive(grp, blk, ++ep);   // publish h-plane init
  bar_wait(grp, ep);

  // ---- pre-loop: accL0 = W_ih0@x[0] + W_hh0@h0init; accL1 = W_hh1@h1init ----
  float accL0[8], accL1[8];
#pragma unroll
  for (int r = 0; r < 8; ++r) { accL0[r] = 0.f; accL1[r] = 0.f; }
  dot8_x16(x + ((size_t)b * Tc + 0) * NINc + kg * 16, &wl0[kg * 16], 768, accL0);
  dot8_a32(h0p + (kg * 32) * Bc + b, &wl0[NINc + kg * 32], 768, accL0);
  dot8_a32(h1p + (kg * 32) * Bc + b, &wl1[Hc + kg * 32], 1024, accL1);

  for (int t = 0; t < Tc; ++t) {
    const bool upn = (t + 1 < Tc) && UPAT(t + 1);

    // ---- 1. feedback part of L0[t] (only when scheduled sampling) ----
    if (t > 0 && UPAT(t))
      dot8_a16(outT + (kg * 16) * Bc + b, &wl0[kg * 16], 768, accL0);

    // ---- 2. L0 cell: distributed gates (512 thr) + finish (128 thr) ----
    write_plane(pbuf, accL0, kg, b);
    __syncthreads();
    if (tid < 512) {
      const int r = kg & 7;   // kg<8 for tid<512
      float s = sum_planes_f(pbuf, r, b) + biasesF[0][r];
      gbuf[r * 64 + b] = ((r & 3) == 2) ? tanhf(s) : fsig(s);
    }
    __syncthreads();
    if (tid < 128) {
      float si = gbuf[(cu * 4 + 0) * 64 + b];
      float sf = gbuf[(cu * 4 + 1) * 64 + b];
      float sg = gbuf[(cu * 4 + 2) * 64 + b];
      float so = gbuf[(cu * 4 + 3) * 64 + b];
      double cn = (double)sf * c0r + (double)(si * sg);
      c0r = cn;
      stg1(&h0p[(j0 + cu) * Bc + b], so * tanhf((float)cn));
    }
#pragma unroll
    for (int r = 0; r < 8; ++r) accL0[r] = 0.f;
    bar_arrive(grp, blk, ++ep);

    // ---- 3. hidden behind bar1: x[t+1] part of L0[t+1] (cached) ----
    if (t + 1 < Tc && !upn)
      dot8_x16(x + ((size_t)b * Tc + (t + 1)) * NINc + kg * 16, &wl0[kg * 16], 768, accL0);

    bar_wait(grp, ep);   // h0[t] visible

    // ---- 5. fused CD: one h0[t] stream -> accL1 (W_ih1) + accL0 (W_hh0, t+1) ----
    dot_cd32(h0p + (kg * 32) * Bc + b,
             &wl1[kg * 32], 1024, accL1,
             &wl0[NINc + kg * 32], 768, accL0);

    // ---- 6. L1 cell: distributed gates + finish, publish h1[t] ----
    write_plane(pbuf, accL1, kg, b);
    __syncthreads();
    if (tid < 512) {
      const int r = kg & 7;
      float s = sum_planes_f(pbuf, r, b) + biasesF[1][r];
      gbuf[r * 64 + b] = ((r & 3) == 2) ? tanhf(s) : fsig(s);
    }
    __syncthreads();
    if (tid < 128) {
      float si = gbuf[(cu * 4 + 0) * 64 + b];
      float sf = gbuf[(cu * 4 + 1) * 64 + b];
      float sg = gbuf[(cu * 4 + 2) * 64 + b];
      float so = gbuf[(cu * 4 + 3) * 64 + b];
      double cn = (double)sf * c1r + (double)(si * sg);
      c1r = cn;
      stg1(&h1p[(j0 + cu) * Bc + b], so * tanhf((float)cn));
    }
#pragma unroll
    for (int r = 0; r < 8; ++r) accL1[r] = 0.f;
    bar_arrive(grp, blk, ++ep);
    bar_wait(grp, ep);   // h1[t] visible

    // ---- 8. fused EB: one h1[t] stream -> head partial + accL1 (W_hh1, t+1) ----
    {
      float hs = 0.f;
      dot_eb32(h1p + (kg * 32) * Bc + b,
               &wl1[Hc + kg * 32], 1024, accL1,
               &whd[kg * 32], &hs);
      pbuf[kg * 64 + b] = hs;
    }
    __syncthreads();

    // ---- 9. head finish; out + feedback publish ----
    if (tid < 64) {
      float s = bembs;
#pragma unroll
      for (int pl = 0; pl < NWAVE; ++pl) s += pbuf[pl * 64 + b];
      float o = tanhf(s);
      stg1(&outT[blk * Bc + b], o);                    // feedback buffer [NOUT][B]
      out[((size_t)b * Tc + t) * NOUTc + blk] = o;     // final output [B,T,NOUT]
    }
    if (upn) {
      bar_arrive(grp, blk, ++ep);                      // publish out[t]
      bar_wait(grp, ep);
    } else if (t + 1 < Tc) {
      __syncthreads();                                 // pbuf reuse guard
    }
  }
}

extern "C" void kernel_launch(void* const* d_in, const int* in_sizes, int n_in,
                              void* d_out, int out_size, void* d_ws, size_t ws_size,
                              hipStream_t stream) {
  const float* x    = (const float*)d_in[0];
  const float* h0   = (const float*)d_in[1];
  const float* c0   = (const float*)d_in[2];
  const float* Wih0 = (const float*)d_in[3];
  const float* Wih1 = (const float*)d_in[4];
  const float* Whh  = (const float*)d_in[5];
  const float* bih  = (const float*)d_in[6];
  const float* bhh  = (const float*)d_in[7];
  const float* Wemb = (const float*)d_in[8];
  const float* bemb = (const float*)d_in[9];
  const unsigned char* uprev = (const unsigned char*)d_in[10];
  float* out = (float*)d_out;
  float* ws  = (float*)d_ws;

  // zero the barrier control region (first 16 KiB) every call (inside graph)
  hipMemsetAsync(d_ws, 0, 16384, stream);

  void* args[] = {(void*)&x, (void*)&h0, (void*)&c0, (void*)&Wih0, (void*)&Wih1,
                  (void*)&Whh, (void*)&bih, (void*)&bhh, (void*)&Wemb, (void*)&bemb,
                  (void*)&uprev, (void*)&out, (void*)&ws};
  hipLaunchCooperativeKernel((void*)lstm_seq_kernel, dim3(NBLK), dim3(NTHR),
                             args, 0, stream);
}